// Round 6
// baseline (373.417 us; speedup 1.0000x reference)
//
#include <hip/hip_runtime.h>
#include <math.h>

// Shapes fixed by setup_inputs: B=1024, N=200000, D=128, K=5
#define D128 128
#define TOPK 5
#define NP 200704        // N padded to 64
#define NCH2 12544       // NP/16 : 16-key chunks
#define NSTRIP 392       // NP/512 strips (pass-A block x-dim)
#define MARGIN 0.008f    // bf16-sim (<=3.9e-3) + fp16-storage (<=4.9e-4) + slack
#define CAP 1024         // candidate-list capacity per query (overflow -> full scan)

typedef __attribute__((ext_vector_type(8))) short short8;     // 8 bf16 = 4 VGPR
typedef __attribute__((ext_vector_type(8))) _Float16 half8;   // 8 fp16 = 4 VGPR
typedef __attribute__((ext_vector_type(4))) float f32x4;      // MFMA acc

__device__ __forceinline__ short f2bf(float f) {
    union { float f; unsigned u; } c; c.f = f;
    unsigned u = c.u + 0x7FFFu + ((c.u >> 16) & 1u);
    return (short)(u >> 16);
}

// Guarded branch-free descending insert (val+idx). Precondition: nv > v[NN-1].
template <int NN>
__device__ __forceinline__ void insertg(float (&v)[NN], int (&x)[NN], float nv, int nj) {
    bool g[NN];
    #pragma unroll
    for (int i = 0; i < NN; ++i) g[i] = nv > v[i];
    #pragma unroll
    for (int i = NN - 1; i > 0; --i) {
        v[i] = g[i - 1] ? v[i - 1] : (g[i] ? nv : v[i]);
        x[i] = g[i - 1] ? x[i - 1] : (g[i] ? nj : x[i]);
    }
    v[0] = g[0] ? nv : v[0];
    x[0] = g[0] ? nj : x[0];
}
// Values-only variant. Precondition: nv > v[NN-1].
template <int NN>
__device__ __forceinline__ void insertv(float (&v)[NN], float nv) {
    bool g[NN];
    #pragma unroll
    for (int i = 0; i < NN; ++i) g[i] = nv > v[i];
    #pragma unroll
    for (int i = NN - 1; i > 0; --i)
        v[i] = g[i - 1] ? v[i - 1] : (g[i] ? nv : v[i]);
    v[0] = g[0] ? nv : v[0];
}

// ---------------- Kernel A: normalize queries -> fp32 qn + bf16 qbf ----------------
__global__ void qnorm_kernel(const float* __restrict__ q, float* __restrict__ qn,
                             short* __restrict__ qbf) {
    int b = blockIdx.x, t = threadIdx.x;   // 64 threads
    float v0 = q[(size_t)b * D128 + t];
    float v1 = q[(size_t)b * D128 + t + 64];
    float ss = v0 * v0 + v1 * v1;
    #pragma unroll
    for (int off = 32; off > 0; off >>= 1) ss += __shfl_xor(ss, off, 64);
    float scale = 1.0f / fmaxf(sqrtf(ss), 1e-12f);
    float a0 = v0 * scale, a1 = v1 * scale;
    qn[(size_t)b * D128 + t] = a0;
    qn[(size_t)b * D128 + t + 64] = a1;
    qbf[(size_t)b * D128 + t] = f2bf(a0);
    qbf[(size_t)b * D128 + t + 64] = f2bf(a1);
}

// ---------------- Kernel B: memory fp32 -> bf16, zero-padded to NP rows ----------------
__global__ void mconv_kernel(const float* __restrict__ mem, short* __restrict__ mbf, int N) {
    int idx = blockIdx.x * 256 + threadIdx.x;     // one short8 per thread
    if (idx >= NP * 16) return;
    int row = idx >> 4, seg = idx & 15;
    short8 out;
    if (row < N) {
        const float* p = mem + (size_t)row * D128 + seg * 8;
        #pragma unroll
        for (int i = 0; i < 8; ++i) out[i] = f2bf(p[i]);
    } else {
        #pragma unroll
        for (int i = 0; i < 8; ++i) out[i] = 0;
    }
    *(short8*)(mbf + (size_t)row * D128 + seg * 8) = out;
}

#define MFMA16(a, b, c) __builtin_amdgcn_mfma_f32_16x16x32_bf16(a, b, c, 0, 0, 0)

// ---------------- Kernel C: MFMA sweep, per-(query, 16-key-chunk) max ----------------
// Block = 4 waves x 128 queries = 512 queries x one 512-key strip (8 rounds of 64 keys).
// 8 B-frags per wave (128 VGPR) -> 32 MFMA per 4 ds_read_b128, and only 2 query-group
// passes over the 51.4 MB key bank (halved L2/L3 traffic vs 4-frag version).
// Register-prefetch pipeline distance 2. Per-16-key-tile C-fragment maxima are reduced
// across quads and buffered in sC (stride 40 fp16, 16B-aligned), flushed 64 B/query.
__global__ __launch_bounds__(256, 2) void simtopk_max(
    const short* __restrict__ qbf, const short* __restrict__ mbf,
    _Float16* __restrict__ candT) {
    __shared__ short sK[64 * 136];        // 17.4 KB key tile (272B stride)
    __shared__ _Float16 sC[512 * 40];     // 40 KB chunk-max tile (32 used of 40)
    const int strip = blockIdx.x;         // 0..391
    const int qsg = blockIdx.y;           // 0..1
    const int t = threadIdx.x, w = t >> 6, lane = t & 63;
    const int n = lane & 15, quad = lane >> 4;
    const int qwbase = qsg * 512 + w * 128;

    // Resident B-frags: 8 q-tiles x 4 K-steps (128 VGPR)
    short8 bq[8][4];
    #pragma unroll
    for (int f = 0; f < 8; ++f) {
        const short* qrow = qbf + (size_t)(qwbase + f * 16 + n) * D128 + quad * 8;
        #pragma unroll
        for (int s = 0; s < 4; ++s) bq[f][s] = *(const short8*)(qrow + s * 32);
    }

    const size_t k0 = (size_t)strip * 512;
    const int srow = t >> 4, scol = t & 15;
    const short* gbase = mbf + (k0 + srow) * D128 + scol * 8;

    short8 r0, r1, r2, r3;
    r0 = *(const short8*)(gbase + (size_t)0 * 16 * D128);
    r1 = *(const short8*)(gbase + (size_t)1 * 16 * D128);
    r2 = *(const short8*)(gbase + (size_t)2 * 16 * D128);
    r3 = *(const short8*)(gbase + (size_t)3 * 16 * D128);
    *(short8*)(&sK[(srow +  0) * 136 + scol * 8]) = r0;
    *(short8*)(&sK[(srow + 16) * 136 + scol * 8]) = r1;
    *(short8*)(&sK[(srow + 32) * 136 + scol * 8]) = r2;
    *(short8*)(&sK[(srow + 48) * 136 + scol * 8]) = r3;
    __syncthreads();
    {
        const short* g = gbase + (size_t)1 * 64 * D128;
        r0 = *(const short8*)(g + (size_t)0 * 16 * D128);
        r1 = *(const short8*)(g + (size_t)1 * 16 * D128);
        r2 = *(const short8*)(g + (size_t)2 * 16 * D128);
        r3 = *(const short8*)(g + (size_t)3 * 16 * D128);
    }

    for (int round = 0; round < 8; ++round) {
        #pragma unroll
        for (int tt = 0; tt < 4; ++tt) {
            const short* ab = &sK[(tt * 16 + n) * 136 + quad * 8];
            short8 a0 = *(const short8*)(ab);
            short8 a1 = *(const short8*)(ab + 32);
            short8 a2 = *(const short8*)(ab + 64);
            short8 a3 = *(const short8*)(ab + 96);
            f32x4 c[8];
            #pragma unroll
            for (int f = 0; f < 8; ++f) c[f] = (f32x4){0.f, 0.f, 0.f, 0.f};
            #pragma unroll
            for (int f = 0; f < 8; ++f) c[f] = MFMA16(a0, bq[f][0], c[f]);
            #pragma unroll
            for (int f = 0; f < 8; ++f) c[f] = MFMA16(a1, bq[f][1], c[f]);
            #pragma unroll
            for (int f = 0; f < 8; ++f) c[f] = MFMA16(a2, bq[f][2], c[f]);
            #pragma unroll
            for (int f = 0; f < 8; ++f) c[f] = MFMA16(a3, bq[f][3], c[f]);
            // per-tile (=16-key-chunk) max per query frag, reduced across quads
            float m[8];
            #pragma unroll
            for (int f = 0; f < 8; ++f) {
                float v = fmaxf(fmaxf(c[f][0], c[f][1]), fmaxf(c[f][2], c[f][3]));
                v = fmaxf(v, __shfl_xor(v, 16, 64));
                v = fmaxf(v, __shfl_xor(v, 32, 64));
                m[f] = v;
            }
            // quad g writes frags g and g+4 (values wave-uniform after reduction)
            {
                float ma = (quad == 0) ? m[0] : (quad == 1) ? m[1] : (quad == 2) ? m[2] : m[3];
                float mb = (quad == 0) ? m[4] : (quad == 1) ? m[5] : (quad == 2) ? m[6] : m[7];
                sC[(w * 128 + quad * 16 + n) * 40 + round * 4 + tt] = (_Float16)ma;
                sC[(w * 128 + (quad + 4) * 16 + n) * 40 + round * 4 + tt] = (_Float16)mb;
            }
        }
        if (round < 7) {
            __syncthreads();
            *(short8*)(&sK[(srow +  0) * 136 + scol * 8]) = r0;
            *(short8*)(&sK[(srow + 16) * 136 + scol * 8]) = r1;
            *(short8*)(&sK[(srow + 32) * 136 + scol * 8]) = r2;
            *(short8*)(&sK[(srow + 48) * 136 + scol * 8]) = r3;
            __syncthreads();
            if (round < 6) {
                const short* g = gbase + (size_t)(round + 2) * 64 * D128;
                r0 = *(const short8*)(g + (size_t)0 * 16 * D128);
                r1 = *(const short8*)(g + (size_t)1 * 16 * D128);
                r2 = *(const short8*)(g + (size_t)2 * 16 * D128);
                r3 = *(const short8*)(g + (size_t)3 * 16 * D128);
            }
        }
    }

    __syncthreads();
    // Flush: thread t handles local queries t and t+256 -> 32 fp16 (64 B) each
    #pragma unroll
    for (int j = 0; j < 2; ++j) {
        int lq = t + j * 256;
        int q = qsg * 512 + lq;
        short* dst = (short*)candT + (size_t)q * NCH2 + strip * 32;
        #pragma unroll
        for (int k = 0; k < 4; ++k)
            *(short8*)(dst + k * 8) = *(const short8*)(&sC[lq * 40 + k * 8]);
    }
}

// ---------------- Kernel D: streamed threshold + batched exact rescore ----------------
// One 256-thread block per query; tiny LDS (~3 KB) -> 8 blocks/CU.
//   P1: stream candT row; per-thread top-6 -> per-wave 6th-largest. thr =
//       max_w(wave 6th) - 2*MARGIN. (subset 6th-largest <= global 6th-largest, so
//       the filter keeps a superset of the provably-sufficient set: 6 distinct chunks
//       >= t6 give >=5 valid keys with exact sim >= t6-MARGIN => any top-5 key's
//       stored chunk max >= t5-MARGIN >= t6-2*MARGIN >= thr.)
//   P2: re-stream (L2-hot), append passing chunks (overflow -> full scan).
//   P3: batched fp32-exact rescore: 16 lanes per chunk, one key per lane.
//   P4: wave extraction + block merge -> softmax/gather/normalize.
__global__ __launch_bounds__(256, 8) void finalize_batch(
    const _Float16* __restrict__ candT, const float* __restrict__ mem,
    const float* __restrict__ qn, const int* __restrict__ index_map,
    const int* __restrict__ excl,
    float* __restrict__ outR, float* __restrict__ outD, float* __restrict__ outW, int N) {
    const int q = blockIdx.x, t = threadIdx.x;
    const int w = t >> 6, lane = t & 63;

    __shared__ float sQ[D128];
    __shared__ float sThrW[4];
    __shared__ unsigned short sList[CAP];
    __shared__ int sCnt, sOv;
    __shared__ float sWv[4 * TOPK];
    __shared__ int   sWk[4 * TOPK];
    __shared__ float sW[TOPK];
    __shared__ int   sJ[TOPK];

    if (t < 128) sQ[t] = qn[(size_t)q * D128 + t];
    if (t == 0) { sCnt = 0; sOv = 0; }
    const half8* crow8 = (const half8*)(candT + (size_t)q * NCH2);   // 1568 vectors

    // ---- P1: streamed per-thread top-6, then wave 6th-largest ----
    float pv[6];
    #pragma unroll
    for (int i = 0; i < 6; ++i) pv[i] = -3e38f;
    for (int i = t; i < NCH2 / 8; i += 256) {
        half8 v8 = crow8[i];
        #pragma unroll
        for (int j = 0; j < 8; ++j) {
            float v = (float)v8[j];
            if (v > pv[5]) insertv<6>(pv, v);
        }
    }
    {
        float b6 = -3e38f;
        #pragma unroll
        for (int r = 0; r < 6; ++r) {
            float bv = pv[0];
            #pragma unroll
            for (int off = 32; off > 0; off >>= 1) bv = fmaxf(bv, __shfl_xor(bv, off, 64));
            int ml = (pv[0] == bv) ? lane : 64;
            #pragma unroll
            for (int off = 32; off > 0; off >>= 1) ml = min(ml, __shfl_xor(ml, off, 64));
            if (lane == ml) {
                #pragma unroll
                for (int i = 0; i < 5; ++i) pv[i] = pv[i + 1];
                pv[5] = -3e38f;
            }
            b6 = bv;   // after r=5: wave-local 6th-largest
        }
        if (lane == 0) sThrW[w] = b6;
    }
    __syncthreads();
    const float thr = fmaxf(fmaxf(sThrW[0], sThrW[1]), fmaxf(sThrW[2], sThrW[3]))
                      - 2.0f * MARGIN;

    // ---- P2: candidate list (second stream, L2-hot) ----
    for (int i = t; i < NCH2 / 8; i += 256) {
        half8 v8 = crow8[i];
        #pragma unroll
        for (int j = 0; j < 8; ++j) {
            if ((float)v8[j] >= thr) {
                int p = atomicAdd(&sCnt, 1);
                if (p < CAP) sList[p] = (unsigned short)(i * 8 + j); else sOv = 1;
            }
        }
    }
    __syncthreads();
    const int ov = sOv;
    const int cnt = ov ? NCH2 : min(sCnt, CAP);

    // ---- P3: batched fp32-exact rescore ----
    const int exq = excl[q];
    float tv[TOPK]; int ti[TOPK];
    #pragma unroll
    for (int i = 0; i < TOPK; ++i) { tv[i] = -3e38f; ti[i] = -1; }
    const int rounds = (cnt + 15) >> 4;
    for (int r = 0; r < rounds; ++r) {
        int slot = r * 16 + (t >> 4);
        int ch = (slot < cnt) ? (ov ? slot : (int)sList[slot]) : -1;
        int key = ch * 16 + (t & 15);
        float v = -3e38f;
        if (ch >= 0 && key < N && index_map[key] != exq) {
            const float4* mr = (const float4*)(mem + (size_t)key * D128);
            const float4* qv = (const float4*)sQ;
            float acc = 0.f;
            #pragma unroll
            for (int d = 0; d < 32; ++d) {
                float4 a = mr[d], b = qv[d];
                acc += a.x * b.x + a.y * b.y + a.z * b.z + a.w * b.w;
            }
            v = acc;
        }
        if (v > tv[TOPK - 1]) insertg<TOPK>(tv, ti, v, key);
    }

    // ---- P4: wave extraction (tie-break smaller key), block merge, outputs ----
    #pragma unroll
    for (int r = 0; r < TOPK; ++r) {
        float bv = tv[0]; int bk = ti[0];
        #pragma unroll
        for (int off = 32; off > 0; off >>= 1) {
            float ovv = __shfl_xor(bv, off, 64);
            int   okk = __shfl_xor(bk, off, 64);
            if (ovv > bv || (ovv == bv && (unsigned)okk < (unsigned)bk)) { bv = ovv; bk = okk; }
        }
        if (tv[0] == bv && ti[0] == bk) {
            #pragma unroll
            for (int i = 0; i < TOPK - 1; ++i) { tv[i] = tv[i + 1]; ti[i] = ti[i + 1]; }
            tv[TOPK - 1] = -3e38f; ti[TOPK - 1] = -1;
        }
        if (lane == 0) { sWv[w * TOPK + r] = bv; sWk[w * TOPK + r] = bk; }
    }
    __syncthreads();
    if (t == 0) {
        float bv[TOPK]; int bi[TOPK];
        #pragma unroll
        for (int i = 0; i < TOPK; ++i) { bv[i] = -3e38f; bi[i] = -1; }
        for (int j = 0; j < 4 * TOPK; ++j) {
            float v = sWv[j];
            if (v > bv[TOPK - 1]) insertg<TOPK>(bv, bi, v, sWk[j]);
        }
        float m = bv[0], ex[TOPK], sum = 0.f;
        #pragma unroll
        for (int k = 0; k < TOPK; ++k) { ex[k] = __expf((bv[k] - m) * 10.0f); sum += ex[k]; }
        float inv = 1.0f / sum;
        #pragma unroll
        for (int k = 0; k < TOPK; ++k) {
            float wk = ex[k] * inv;
            sW[k] = wk; sJ[k] = bi[k];
            outW[(size_t)q * TOPK + k] = wk;
        }
        outD[q] = 1.0f - bv[0];
    }
    __syncthreads();
    if (t < 64) {
        float r0 = 0.f, r1 = 0.f;
        #pragma unroll
        for (int k = 0; k < TOPK; ++k) {
            const float* mr = mem + (size_t)sJ[k] * D128;
            r0 += sW[k] * mr[t];
            r1 += sW[k] * mr[t + 64];
        }
        float ss = r0 * r0 + r1 * r1;
        #pragma unroll
        for (int off = 32; off > 0; off >>= 1) ss += __shfl_xor(ss, off, 64);
        float scale = 1.0f / fmaxf(sqrtf(ss), 1e-12f);
        outR[(size_t)q * D128 + t]      = r0 * scale;
        outR[(size_t)q * D128 + t + 64] = r1 * scale;
    }
}

extern "C" void kernel_launch(void* const* d_in, const int* in_sizes, int n_in,
                              void* d_out, int out_size, void* d_ws, size_t ws_size,
                              hipStream_t stream) {
    const float* query  = (const float*)d_in[0];   // [B,128] fp32
    const float* memory = (const float*)d_in[1];   // [N,128] fp32 (pre-normalized)
    const int* index_map = (const int*)d_in[2];    // [N] int32
    const int* excl      = (const int*)d_in[3];    // [B] int32

    const int B = in_sizes[3];                     // 1024
    const int N = in_sizes[2];                     // 200000

    // Workspace:
    //   qn    fp32 [B*128]         @ 0          (512 KB)
    //   qbf   bf16 [B*128]         @ 524288     (256 KB)
    //   mbf   bf16 [NP*128]        @ 786432     (51.4 MB)
    //   candT fp16 [B][NCH2]       @ 52166656   (25.7 MB)   total ~77.9 MB
    char* ws = (char*)d_ws;
    float*    qn    = (float*)(ws);
    short*    qbf   = (short*)(ws + 524288);
    short*    mbf   = (short*)(ws + 786432);
    _Float16* candT = (_Float16*)(ws + 52166656);

    float* outR = (float*)d_out;                   // [B,128]
    float* outD = outR + (size_t)B * D128;         // [B]
    float* outW = outD + B;                        // [B,5]

    qnorm_kernel<<<B, 64, 0, stream>>>(query, qn, qbf);
    mconv_kernel<<<(NP * 16 + 255) / 256, 256, 0, stream>>>(memory, mbf, N);
    dim3 gridC(NSTRIP, 2);
    simtopk_max<<<gridC, 256, 0, stream>>>(qbf, mbf, candT);
    finalize_batch<<<B, 256, 0, stream>>>(candT, memory, qn, index_map, excl,
                                          outR, outD, outW, N);
}

// Round 7
// 303.774 us; speedup vs baseline: 1.2293x; 1.2293x over previous
//
#include <hip/hip_runtime.h>
#include <math.h>

// Shapes fixed by setup_inputs: B=1024, N=200000, D=128, K=5
#define D128 128
#define TOPK 5
#define NP 200704        // N padded to 64
#define NCH2 12544       // NP/16 : 16-key chunks
#define NSTRIP 392       // NP/512 strips (pass-A block x-dim)
#define MARGIN 0.008f    // bf16-sim (<=3.9e-3) + fp16-storage (<=4.9e-4) + slack
#define CAP 1024         // candidate-list capacity per query (overflow -> full scan)

typedef __attribute__((ext_vector_type(8))) short short8;     // 8 bf16 = 4 VGPR
typedef __attribute__((ext_vector_type(8))) _Float16 half8;   // 8 fp16 = 4 VGPR
typedef __attribute__((ext_vector_type(4))) float f32x4;      // MFMA acc

__device__ __forceinline__ short f2bf(float f) {
    union { float f; unsigned u; } c; c.f = f;
    unsigned u = c.u + 0x7FFFu + ((c.u >> 16) & 1u);
    return (short)(u >> 16);
}

// Guarded branch-free descending insert (val+idx). Precondition: nv > v[NN-1].
template <int NN>
__device__ __forceinline__ void insertg(float (&v)[NN], int (&x)[NN], float nv, int nj) {
    bool g[NN];
    #pragma unroll
    for (int i = 0; i < NN; ++i) g[i] = nv > v[i];
    #pragma unroll
    for (int i = NN - 1; i > 0; --i) {
        v[i] = g[i - 1] ? v[i - 1] : (g[i] ? nv : v[i]);
        x[i] = g[i - 1] ? x[i - 1] : (g[i] ? nj : x[i]);
    }
    v[0] = g[0] ? nv : v[0];
    x[0] = g[0] ? nj : x[0];
}
// Values-only variant. Precondition: nv > v[NN-1].
template <int NN>
__device__ __forceinline__ void insertv(float (&v)[NN], float nv) {
    bool g[NN];
    #pragma unroll
    for (int i = 0; i < NN; ++i) g[i] = nv > v[i];
    #pragma unroll
    for (int i = NN - 1; i > 0; --i)
        v[i] = g[i - 1] ? v[i - 1] : (g[i] ? nv : v[i]);
    v[0] = g[0] ? nv : v[0];
}

// ---------------- Kernel A: normalize queries -> fp32 qn + bf16 qbf ----------------
__global__ void qnorm_kernel(const float* __restrict__ q, float* __restrict__ qn,
                             short* __restrict__ qbf) {
    int b = blockIdx.x, t = threadIdx.x;   // 64 threads
    float v0 = q[(size_t)b * D128 + t];
    float v1 = q[(size_t)b * D128 + t + 64];
    float ss = v0 * v0 + v1 * v1;
    #pragma unroll
    for (int off = 32; off > 0; off >>= 1) ss += __shfl_xor(ss, off, 64);
    float scale = 1.0f / fmaxf(sqrtf(ss), 1e-12f);
    float a0 = v0 * scale, a1 = v1 * scale;
    qn[(size_t)b * D128 + t] = a0;
    qn[(size_t)b * D128 + t + 64] = a1;
    qbf[(size_t)b * D128 + t] = f2bf(a0);
    qbf[(size_t)b * D128 + t + 64] = f2bf(a1);
}

// ---------------- Kernel B: memory fp32 -> bf16, zero-padded to NP rows ----------------
__global__ void mconv_kernel(const float* __restrict__ mem, short* __restrict__ mbf, int N) {
    int idx = blockIdx.x * 256 + threadIdx.x;     // one short8 per thread
    if (idx >= NP * 16) return;
    int row = idx >> 4, seg = idx & 15;
    short8 out;
    if (row < N) {
        const float4* p = (const float4*)(mem + (size_t)row * D128 + seg * 8);
        float4 a = p[0], b = p[1];
        out[0] = f2bf(a.x); out[1] = f2bf(a.y); out[2] = f2bf(a.z); out[3] = f2bf(a.w);
        out[4] = f2bf(b.x); out[5] = f2bf(b.y); out[6] = f2bf(b.z); out[7] = f2bf(b.w);
    } else {
        #pragma unroll
        for (int i = 0; i < 8; ++i) out[i] = 0;
    }
    *(short8*)(mbf + (size_t)row * D128 + seg * 8) = out;
}

#define MFMA16(a, b, c) __builtin_amdgcn_mfma_f32_16x16x32_bf16(a, b, c, 0, 0, 0)

// ---------------- Kernel C: MFMA sweep, per-(query, 16-key-chunk) max ----------------
// R5-identical (known-good ~60 us). Block = 4 waves x 64 queries = 256 queries x one
// 512-key strip (8 rounds of 64 keys = 4 MFMA tiles each). Register-prefetch pipeline
// distance 2. Per-tile C-fragment maxima reduced across quads, buffered in sC
// (stride 40 fp16), flushed 64 B contiguous per query -> candT[q][chunk].
__global__ __launch_bounds__(256, 3) void simtopk_max(
    const short* __restrict__ qbf, const short* __restrict__ mbf,
    _Float16* __restrict__ candT) {
    __shared__ short sK[64 * 136];        // 17.4 KB key tile (272B stride)
    __shared__ _Float16 sC[256 * 40];     // 20 KB chunk-max tile (32 used of 40)
    const int strip = blockIdx.x;         // 0..391
    const int qsg = blockIdx.y;           // 0..3
    const int t = threadIdx.x, w = t >> 6, lane = t & 63;
    const int n = lane & 15, quad = lane >> 4;
    const int qbase = qsg * 256 + w * 64;

    short8 bq[4][4];
    #pragma unroll
    for (int f = 0; f < 4; ++f) {
        const short* qrow = qbf + (size_t)(qbase + f * 16 + n) * D128 + quad * 8;
        #pragma unroll
        for (int s = 0; s < 4; ++s) bq[f][s] = *(const short8*)(qrow + s * 32);
    }

    const size_t k0 = (size_t)strip * 512;
    const int srow = t >> 4, scol = t & 15;
    const short* gbase = mbf + (k0 + srow) * D128 + scol * 8;

    short8 r0, r1, r2, r3;
    r0 = *(const short8*)(gbase + (size_t)0 * 16 * D128);
    r1 = *(const short8*)(gbase + (size_t)1 * 16 * D128);
    r2 = *(const short8*)(gbase + (size_t)2 * 16 * D128);
    r3 = *(const short8*)(gbase + (size_t)3 * 16 * D128);
    *(short8*)(&sK[(srow +  0) * 136 + scol * 8]) = r0;
    *(short8*)(&sK[(srow + 16) * 136 + scol * 8]) = r1;
    *(short8*)(&sK[(srow + 32) * 136 + scol * 8]) = r2;
    *(short8*)(&sK[(srow + 48) * 136 + scol * 8]) = r3;
    __syncthreads();
    {
        const short* g = gbase + (size_t)1 * 64 * D128;
        r0 = *(const short8*)(g + (size_t)0 * 16 * D128);
        r1 = *(const short8*)(g + (size_t)1 * 16 * D128);
        r2 = *(const short8*)(g + (size_t)2 * 16 * D128);
        r3 = *(const short8*)(g + (size_t)3 * 16 * D128);
    }

    for (int round = 0; round < 8; ++round) {
        #pragma unroll
        for (int tt = 0; tt < 4; ++tt) {
            const short* ab = &sK[(tt * 16 + n) * 136 + quad * 8];
            short8 a0 = *(const short8*)(ab);
            short8 a1 = *(const short8*)(ab + 32);
            short8 a2 = *(const short8*)(ab + 64);
            short8 a3 = *(const short8*)(ab + 96);
            f32x4 c0 = {0.f, 0.f, 0.f, 0.f}, c1 = c0, c2 = c0, c3 = c0;
            c0 = MFMA16(a0, bq[0][0], c0);
            c1 = MFMA16(a0, bq[1][0], c1);
            c2 = MFMA16(a0, bq[2][0], c2);
            c3 = MFMA16(a0, bq[3][0], c3);
            c0 = MFMA16(a1, bq[0][1], c0);
            c1 = MFMA16(a1, bq[1][1], c1);
            c2 = MFMA16(a1, bq[2][1], c2);
            c3 = MFMA16(a1, bq[3][1], c3);
            c0 = MFMA16(a2, bq[0][2], c0);
            c1 = MFMA16(a2, bq[1][2], c1);
            c2 = MFMA16(a2, bq[2][2], c2);
            c3 = MFMA16(a2, bq[3][2], c3);
            c0 = MFMA16(a3, bq[0][3], c0);
            c1 = MFMA16(a3, bq[1][3], c1);
            c2 = MFMA16(a3, bq[2][3], c2);
            c3 = MFMA16(a3, bq[3][3], c3);
            float m0 = fmaxf(fmaxf(c0[0], c0[1]), fmaxf(c0[2], c0[3]));
            float m1 = fmaxf(fmaxf(c1[0], c1[1]), fmaxf(c1[2], c1[3]));
            float m2 = fmaxf(fmaxf(c2[0], c2[1]), fmaxf(c2[2], c2[3]));
            float m3 = fmaxf(fmaxf(c3[0], c3[1]), fmaxf(c3[2], c3[3]));
            m0 = fmaxf(m0, __shfl_xor(m0, 16, 64)); m0 = fmaxf(m0, __shfl_xor(m0, 32, 64));
            m1 = fmaxf(m1, __shfl_xor(m1, 16, 64)); m1 = fmaxf(m1, __shfl_xor(m1, 32, 64));
            m2 = fmaxf(m2, __shfl_xor(m2, 16, 64)); m2 = fmaxf(m2, __shfl_xor(m2, 32, 64));
            m3 = fmaxf(m3, __shfl_xor(m3, 16, 64)); m3 = fmaxf(m3, __shfl_xor(m3, 32, 64));
            float msel = (quad == 0) ? m0 : (quad == 1) ? m1 : (quad == 2) ? m2 : m3;
            sC[(w * 64 + quad * 16 + n) * 40 + round * 4 + tt] = (_Float16)msel;
        }
        if (round < 7) {
            __syncthreads();
            *(short8*)(&sK[(srow +  0) * 136 + scol * 8]) = r0;
            *(short8*)(&sK[(srow + 16) * 136 + scol * 8]) = r1;
            *(short8*)(&sK[(srow + 32) * 136 + scol * 8]) = r2;
            *(short8*)(&sK[(srow + 48) * 136 + scol * 8]) = r3;
            __syncthreads();
            if (round < 6) {
                const short* g = gbase + (size_t)(round + 2) * 64 * D128;
                r0 = *(const short8*)(g + (size_t)0 * 16 * D128);
                r1 = *(const short8*)(g + (size_t)1 * 16 * D128);
                r2 = *(const short8*)(g + (size_t)2 * 16 * D128);
                r3 = *(const short8*)(g + (size_t)3 * 16 * D128);
            }
        }
    }

    __syncthreads();
    {
        int q = qsg * 256 + t;
        short* dst = (short*)candT + (size_t)q * NCH2 + strip * 32;
        #pragma unroll
        for (int j = 0; j < 4; ++j)
            *(short8*)(dst + j * 8) = *(const short8*)(&sC[t * 40 + j * 8]);
    }
}

// ---------------- Kernel D: LDS-mirror threshold + batched exact rescore ----------------
// One 512-thread block (8 waves) per query: grid 1024 = exactly 4 blocks/CU;
// 28 KB LDS x 4 = 113 KB -> 32 waves/CU residency (R5 was 16). Same algorithm as R5:
//   P1: exact block 6th-largest chunk max -> thr = t6 - 2*MARGIN (provably complete:
//       6 distinct chunks >= t6 give >=5 valid keys after exclusion with exact sim
//       >= t6-MARGIN, so any true top-5 key's chunk max >= t5-MARGIN >= thr).
//   P2: candidate chunk list from the LDS mirror (overflow -> full scan).
//   P3: batched fp32-exact rescore, 16 lanes per chunk / one key per lane.
//   P4: wave extraction + block merge -> softmax / gather / normalize.
__global__ __launch_bounds__(512, 4) void finalize_batch(
    const _Float16* __restrict__ candT, const float* __restrict__ mem,
    const float* __restrict__ qn, const int* __restrict__ index_map,
    const int* __restrict__ excl,
    float* __restrict__ outR, float* __restrict__ outD, float* __restrict__ outW, int N) {
    const int q = blockIdx.x, t = threadIdx.x;
    const int w = t >> 6, lane = t & 63;

    __shared__ _Float16 sM[NCH2];     // 25.1 KB mirror
    __shared__ float sQ[D128];
    __shared__ unsigned short sList[CAP];
    __shared__ int sCnt, sOv;
    __shared__ float sThr;
    __shared__ float sMrg[8 * 6];
    __shared__ float sWv[8 * TOPK];
    __shared__ int   sWk[8 * TOPK];
    __shared__ float sW[TOPK];
    __shared__ int   sJ[TOPK];

    if (t < 128) sQ[t] = qn[(size_t)q * D128 + t];
    if (t == 0) { sCnt = 0; sOv = 0; }
    {
        const short* crow = (const short*)candT + (size_t)q * NCH2;
        for (int i = t; i < NCH2 / 8; i += 512)
            *(short8*)(&sM[i * 8]) = *(const short8*)(crow + i * 8);
    }
    __syncthreads();

    // ---- P1: per-thread top-6 over strided chunks, wave extraction, block merge ----
    float pv[6];
    #pragma unroll
    for (int i = 0; i < 6; ++i) pv[i] = -3e38f;
    for (int i = t; i < NCH2; i += 512) {
        float v = (float)sM[i];
        if (v > pv[5]) insertv<6>(pv, v);
    }
    #pragma unroll
    for (int r = 0; r < 6; ++r) {
        float bv = pv[0];
        #pragma unroll
        for (int off = 32; off > 0; off >>= 1) bv = fmaxf(bv, __shfl_xor(bv, off, 64));
        int ml = (pv[0] == bv) ? lane : 64;
        #pragma unroll
        for (int off = 32; off > 0; off >>= 1) ml = min(ml, __shfl_xor(ml, off, 64));
        if (lane == ml) {
            #pragma unroll
            for (int i = 0; i < 5; ++i) pv[i] = pv[i + 1];
            pv[5] = -3e38f;
        }
        if (lane == 0) sMrg[w * 6 + r] = bv;
    }
    __syncthreads();
    if (t == 0) {
        float b6[6];
        #pragma unroll
        for (int i = 0; i < 6; ++i) b6[i] = -3e38f;
        for (int j = 0; j < 48; ++j) {
            float v = sMrg[j];
            if (v > b6[5]) insertv<6>(b6, v);
        }
        sThr = b6[5] - 2.0f * MARGIN;
    }
    __syncthreads();

    // ---- P2: candidate list ----
    const float thr = sThr;
    for (int i = t; i < NCH2; i += 512) {
        if ((float)sM[i] >= thr) {
            int p = atomicAdd(&sCnt, 1);
            if (p < CAP) sList[p] = (unsigned short)i; else sOv = 1;
        }
    }
    __syncthreads();
    const int ov = sOv;
    const int cnt = ov ? NCH2 : min(sCnt, CAP);

    // ---- P3: batched fp32-exact rescore (32 chunks per round) ----
    const int exq = excl[q];
    float tv[TOPK]; int ti[TOPK];
    #pragma unroll
    for (int i = 0; i < TOPK; ++i) { tv[i] = -3e38f; ti[i] = -1; }
    const int rounds = (cnt + 31) >> 5;
    for (int r = 0; r < rounds; ++r) {
        int slot = r * 32 + (t >> 4);
        int ch = (slot < cnt) ? (ov ? slot : (int)sList[slot]) : -1;
        int key = ch * 16 + (t & 15);
        float v = -3e38f;
        if (ch >= 0 && key < N && index_map[key] != exq) {
            const float4* mr = (const float4*)(mem + (size_t)key * D128);
            const float4* qv = (const float4*)sQ;
            float acc = 0.f;
            #pragma unroll
            for (int d = 0; d < 32; ++d) {
                float4 a = mr[d], b = qv[d];
                acc += a.x * b.x + a.y * b.y + a.z * b.z + a.w * b.w;
            }
            v = acc;
        }
        if (v > tv[TOPK - 1]) insertg<TOPK>(tv, ti, v, key);
    }

    // ---- P4: wave extraction (tie-break smaller key), block merge, outputs ----
    #pragma unroll
    for (int r = 0; r < TOPK; ++r) {
        float bv = tv[0]; int bk = ti[0];
        #pragma unroll
        for (int off = 32; off > 0; off >>= 1) {
            float ovv = __shfl_xor(bv, off, 64);
            int   okk = __shfl_xor(bk, off, 64);
            if (ovv > bv || (ovv == bv && (unsigned)okk < (unsigned)bk)) { bv = ovv; bk = okk; }
        }
        if (tv[0] == bv && ti[0] == bk) {
            #pragma unroll
            for (int i = 0; i < TOPK - 1; ++i) { tv[i] = tv[i + 1]; ti[i] = ti[i + 1]; }
            tv[TOPK - 1] = -3e38f; ti[TOPK - 1] = -1;
        }
        if (lane == 0) { sWv[w * TOPK + r] = bv; sWk[w * TOPK + r] = bk; }
    }
    __syncthreads();
    if (t == 0) {
        float bv[TOPK]; int bi[TOPK];
        #pragma unroll
        for (int i = 0; i < TOPK; ++i) { bv[i] = -3e38f; bi[i] = -1; }
        for (int j = 0; j < 8 * TOPK; ++j) {
            float v = sWv[j];
            if (v > bv[TOPK - 1]) insertg<TOPK>(bv, bi, v, sWk[j]);
        }
        float m = bv[0], ex[TOPK], sum = 0.f;
        #pragma unroll
        for (int k = 0; k < TOPK; ++k) { ex[k] = __expf((bv[k] - m) * 10.0f); sum += ex[k]; }
        float inv = 1.0f / sum;
        #pragma unroll
        for (int k = 0; k < TOPK; ++k) {
            float wk = ex[k] * inv;
            sW[k] = wk; sJ[k] = bi[k];
            outW[(size_t)q * TOPK + k] = wk;
        }
        outD[q] = 1.0f - bv[0];
    }
    __syncthreads();
    if (t < 64) {
        float r0 = 0.f, r1 = 0.f;
        #pragma unroll
        for (int k = 0; k < TOPK; ++k) {
            const float* mr = mem + (size_t)sJ[k] * D128;
            r0 += sW[k] * mr[t];
            r1 += sW[k] * mr[t + 64];
        }
        float ss = r0 * r0 + r1 * r1;
        #pragma unroll
        for (int off = 32; off > 0; off >>= 1) ss += __shfl_xor(ss, off, 64);
        float scale = 1.0f / fmaxf(sqrtf(ss), 1e-12f);
        outR[(size_t)q * D128 + t]      = r0 * scale;
        outR[(size_t)q * D128 + t + 64] = r1 * scale;
    }
}

extern "C" void kernel_launch(void* const* d_in, const int* in_sizes, int n_in,
                              void* d_out, int out_size, void* d_ws, size_t ws_size,
                              hipStream_t stream) {
    const float* query  = (const float*)d_in[0];   // [B,128] fp32
    const float* memory = (const float*)d_in[1];   // [N,128] fp32 (pre-normalized)
    const int* index_map = (const int*)d_in[2];    // [N] int32
    const int* excl      = (const int*)d_in[3];    // [B] int32

    const int B = in_sizes[3];                     // 1024
    const int N = in_sizes[2];                     // 200000

    // Workspace:
    //   qn    fp32 [B*128]         @ 0          (512 KB)
    //   qbf   bf16 [B*128]         @ 524288     (256 KB)
    //   mbf   bf16 [NP*128]        @ 786432     (51.4 MB)
    //   candT fp16 [B][NCH2]       @ 52166656   (25.7 MB)   total ~77.9 MB
    char* ws = (char*)d_ws;
    float*    qn    = (float*)(ws);
    short*    qbf   = (short*)(ws + 524288);
    short*    mbf   = (short*)(ws + 786432);
    _Float16* candT = (_Float16*)(ws + 52166656);

    float* outR = (float*)d_out;                   // [B,128]
    float* outD = outR + (size_t)B * D128;         // [B]
    float* outW = outD + B;                        // [B,5]

    qnorm_kernel<<<B, 64, 0, stream>>>(query, qn, qbf);
    mconv_kernel<<<(NP * 16 + 255) / 256, 256, 0, stream>>>(memory, mbf, N);
    dim3 gridC(NSTRIP, 4);
    simtopk_max<<<gridC, 256, 0, stream>>>(qbf, mbf, candT);
    finalize_batch<<<B, 512, 0, stream>>>(candT, memory, qn, index_map, excl,
                                          outR, outD, outW, N);
}

// Round 8
// 302.855 us; speedup vs baseline: 1.2330x; 1.0030x over previous
//
#include <hip/hip_runtime.h>
#include <math.h>

// Shapes fixed by setup_inputs: B=1024, N=200000, D=128, K=5
#define D128 128
#define TOPK 5
#define NP 200704        // N padded to 64
#define NCH2 12544       // NP/16 : 16-key chunks
#define NSTRIP 392       // NP/512 strips (pass-A block x-dim; 32 chunks per strip)
#define MARGIN 0.008f    // bf16-sim (<=3.9e-3) + fp16-storage (<=4.9e-4) + slack
#define CAP 1024         // chunk candidate capacity per query (overflow -> full scan)

typedef __attribute__((ext_vector_type(8))) short short8;     // 8 bf16 = 4 VGPR
typedef __attribute__((ext_vector_type(8))) _Float16 half8;   // 8 fp16 = 4 VGPR
typedef __attribute__((ext_vector_type(4))) float f32x4;      // MFMA acc

__device__ __forceinline__ short f2bf(float f) {
    union { float f; unsigned u; } c; c.f = f;
    unsigned u = c.u + 0x7FFFu + ((c.u >> 16) & 1u);
    return (short)(u >> 16);
}

// Guarded branch-free descending insert (val+idx). Precondition: nv > v[NN-1].
template <int NN>
__device__ __forceinline__ void insertg(float (&v)[NN], int (&x)[NN], float nv, int nj) {
    bool g[NN];
    #pragma unroll
    for (int i = 0; i < NN; ++i) g[i] = nv > v[i];
    #pragma unroll
    for (int i = NN - 1; i > 0; --i) {
        v[i] = g[i - 1] ? v[i - 1] : (g[i] ? nv : v[i]);
        x[i] = g[i - 1] ? x[i - 1] : (g[i] ? nj : x[i]);
    }
    v[0] = g[0] ? nv : v[0];
    x[0] = g[0] ? nj : x[0];
}
// Values-only variant. Precondition: nv > v[NN-1].
template <int NN>
__device__ __forceinline__ void insertv(float (&v)[NN], float nv) {
    bool g[NN];
    #pragma unroll
    for (int i = 0; i < NN; ++i) g[i] = nv > v[i];
    #pragma unroll
    for (int i = NN - 1; i > 0; --i)
        v[i] = g[i - 1] ? v[i - 1] : (g[i] ? nv : v[i]);
    v[0] = g[0] ? nv : v[0];
}

// ---------------- Kernel A: normalize queries -> fp32 qn + bf16 qbf ----------------
__global__ void qnorm_kernel(const float* __restrict__ q, float* __restrict__ qn,
                             short* __restrict__ qbf) {
    int b = blockIdx.x, t = threadIdx.x;   // 64 threads
    float v0 = q[(size_t)b * D128 + t];
    float v1 = q[(size_t)b * D128 + t + 64];
    float ss = v0 * v0 + v1 * v1;
    #pragma unroll
    for (int off = 32; off > 0; off >>= 1) ss += __shfl_xor(ss, off, 64);
    float scale = 1.0f / fmaxf(sqrtf(ss), 1e-12f);
    float a0 = v0 * scale, a1 = v1 * scale;
    qn[(size_t)b * D128 + t] = a0;
    qn[(size_t)b * D128 + t + 64] = a1;
    qbf[(size_t)b * D128 + t] = f2bf(a0);
    qbf[(size_t)b * D128 + t + 64] = f2bf(a1);
}

// ---------------- Kernel B: memory fp32 -> bf16, zero-padded to NP rows ----------------
__global__ void mconv_kernel(const float* __restrict__ mem, short* __restrict__ mbf, int N) {
    int idx = blockIdx.x * 256 + threadIdx.x;     // one short8 per thread
    if (idx >= NP * 16) return;
    int row = idx >> 4, seg = idx & 15;
    short8 out;
    if (row < N) {
        const float4* p = (const float4*)(mem + (size_t)row * D128 + seg * 8);
        float4 a = p[0], b = p[1];
        out[0] = f2bf(a.x); out[1] = f2bf(a.y); out[2] = f2bf(a.z); out[3] = f2bf(a.w);
        out[4] = f2bf(b.x); out[5] = f2bf(b.y); out[6] = f2bf(b.z); out[7] = f2bf(b.w);
    } else {
        #pragma unroll
        for (int i = 0; i < 8; ++i) out[i] = 0;
    }
    *(short8*)(mbf + (size_t)row * D128 + seg * 8) = out;
}

#define MFMA16(a, b, c) __builtin_amdgcn_mfma_f32_16x16x32_bf16(a, b, c, 0, 0, 0)

// ---------------- Kernel C: MFMA sweep, per-(query,16-key-chunk) max + strip max ----------------
// R5-identical structure (known-good). Block = 4 waves x 64 queries = 256 queries x one
// 512-key strip (8 rounds of 64 keys = 4 MFMA tiles each). Register-prefetch distance 2.
// Flush also reduces each query's 32 chunk maxima to a strip max -> candS[strip][q]
// (coalesced 512 B per block), enabling hierarchical pruning in the finalize kernel.
__global__ __launch_bounds__(256, 3) void simtopk_max(
    const short* __restrict__ qbf, const short* __restrict__ mbf,
    _Float16* __restrict__ candT, _Float16* __restrict__ candS) {
    __shared__ short sK[64 * 136];        // 17.4 KB key tile (272B stride)
    __shared__ _Float16 sC[256 * 40];     // 20 KB chunk-max tile (32 used of 40)
    const int strip = blockIdx.x;         // 0..391
    const int qsg = blockIdx.y;           // 0..3
    const int t = threadIdx.x, w = t >> 6, lane = t & 63;
    const int n = lane & 15, quad = lane >> 4;
    const int qbase = qsg * 256 + w * 64;

    short8 bq[4][4];
    #pragma unroll
    for (int f = 0; f < 4; ++f) {
        const short* qrow = qbf + (size_t)(qbase + f * 16 + n) * D128 + quad * 8;
        #pragma unroll
        for (int s = 0; s < 4; ++s) bq[f][s] = *(const short8*)(qrow + s * 32);
    }

    const size_t k0 = (size_t)strip * 512;
    const int srow = t >> 4, scol = t & 15;
    const short* gbase = mbf + (k0 + srow) * D128 + scol * 8;

    short8 r0, r1, r2, r3;
    r0 = *(const short8*)(gbase + (size_t)0 * 16 * D128);
    r1 = *(const short8*)(gbase + (size_t)1 * 16 * D128);
    r2 = *(const short8*)(gbase + (size_t)2 * 16 * D128);
    r3 = *(const short8*)(gbase + (size_t)3 * 16 * D128);
    *(short8*)(&sK[(srow +  0) * 136 + scol * 8]) = r0;
    *(short8*)(&sK[(srow + 16) * 136 + scol * 8]) = r1;
    *(short8*)(&sK[(srow + 32) * 136 + scol * 8]) = r2;
    *(short8*)(&sK[(srow + 48) * 136 + scol * 8]) = r3;
    __syncthreads();
    {
        const short* g = gbase + (size_t)1 * 64 * D128;
        r0 = *(const short8*)(g + (size_t)0 * 16 * D128);
        r1 = *(const short8*)(g + (size_t)1 * 16 * D128);
        r2 = *(const short8*)(g + (size_t)2 * 16 * D128);
        r3 = *(const short8*)(g + (size_t)3 * 16 * D128);
    }

    for (int round = 0; round < 8; ++round) {
        #pragma unroll
        for (int tt = 0; tt < 4; ++tt) {
            const short* ab = &sK[(tt * 16 + n) * 136 + quad * 8];
            short8 a0 = *(const short8*)(ab);
            short8 a1 = *(const short8*)(ab + 32);
            short8 a2 = *(const short8*)(ab + 64);
            short8 a3 = *(const short8*)(ab + 96);
            f32x4 c0 = {0.f, 0.f, 0.f, 0.f}, c1 = c0, c2 = c0, c3 = c0;
            c0 = MFMA16(a0, bq[0][0], c0);
            c1 = MFMA16(a0, bq[1][0], c1);
            c2 = MFMA16(a0, bq[2][0], c2);
            c3 = MFMA16(a0, bq[3][0], c3);
            c0 = MFMA16(a1, bq[0][1], c0);
            c1 = MFMA16(a1, bq[1][1], c1);
            c2 = MFMA16(a1, bq[2][1], c2);
            c3 = MFMA16(a1, bq[3][1], c3);
            c0 = MFMA16(a2, bq[0][2], c0);
            c1 = MFMA16(a2, bq[1][2], c1);
            c2 = MFMA16(a2, bq[2][2], c2);
            c3 = MFMA16(a2, bq[3][2], c3);
            c0 = MFMA16(a3, bq[0][3], c0);
            c1 = MFMA16(a3, bq[1][3], c1);
            c2 = MFMA16(a3, bq[2][3], c2);
            c3 = MFMA16(a3, bq[3][3], c3);
            float m0 = fmaxf(fmaxf(c0[0], c0[1]), fmaxf(c0[2], c0[3]));
            float m1 = fmaxf(fmaxf(c1[0], c1[1]), fmaxf(c1[2], c1[3]));
            float m2 = fmaxf(fmaxf(c2[0], c2[1]), fmaxf(c2[2], c2[3]));
            float m3 = fmaxf(fmaxf(c3[0], c3[1]), fmaxf(c3[2], c3[3]));
            m0 = fmaxf(m0, __shfl_xor(m0, 16, 64)); m0 = fmaxf(m0, __shfl_xor(m0, 32, 64));
            m1 = fmaxf(m1, __shfl_xor(m1, 16, 64)); m1 = fmaxf(m1, __shfl_xor(m1, 32, 64));
            m2 = fmaxf(m2, __shfl_xor(m2, 16, 64)); m2 = fmaxf(m2, __shfl_xor(m2, 32, 64));
            m3 = fmaxf(m3, __shfl_xor(m3, 16, 64)); m3 = fmaxf(m3, __shfl_xor(m3, 32, 64));
            float msel = (quad == 0) ? m0 : (quad == 1) ? m1 : (quad == 2) ? m2 : m3;
            sC[(w * 64 + quad * 16 + n) * 40 + round * 4 + tt] = (_Float16)msel;
        }
        if (round < 7) {
            __syncthreads();
            *(short8*)(&sK[(srow +  0) * 136 + scol * 8]) = r0;
            *(short8*)(&sK[(srow + 16) * 136 + scol * 8]) = r1;
            *(short8*)(&sK[(srow + 32) * 136 + scol * 8]) = r2;
            *(short8*)(&sK[(srow + 48) * 136 + scol * 8]) = r3;
            __syncthreads();
            if (round < 6) {
                const short* g = gbase + (size_t)(round + 2) * 64 * D128;
                r0 = *(const short8*)(g + (size_t)0 * 16 * D128);
                r1 = *(const short8*)(g + (size_t)1 * 16 * D128);
                r2 = *(const short8*)(g + (size_t)2 * 16 * D128);
                r3 = *(const short8*)(g + (size_t)3 * 16 * D128);
            }
        }
    }

    __syncthreads();
    {
        int q = qsg * 256 + t;
        short* dst = (short*)candT + (size_t)q * NCH2 + strip * 32;
        float mx = -3e38f;
        #pragma unroll
        for (int j = 0; j < 4; ++j) {
            half8 h = *(const half8*)(&sC[t * 40 + j * 8]);
            *(short8*)(dst + j * 8) = *(const short8*)(&h);
            #pragma unroll
            for (int e = 0; e < 8; ++e) mx = fmaxf(mx, (float)h[e]);
        }
        candS[(size_t)strip * 1024 + q] = (_Float16)mx;   // coalesced 512 B/block
    }
}

// ---------------- Kernel D: hierarchical threshold + batched exact rescore ----------------
// One 256-thread block per query; ~4 KB LDS.
//   P1: top-6 over the 392 strip maxima (regs) -> thr = t6strip - 2*MARGIN.
//       Complete: 6 distinct strips >= t6s give 6 distinct chunks (their strip maxima
//       ARE chunk maxima), hence >=6 real keys with exact sim >= t6s-MARGIN, >=5 after
//       exclusion => t5_exact >= t6s-MARGIN. A true top-5 key: its chunk max >= sim-MARGIN
//       >= t5-MARGIN >= thr, and its strip max >= chunk max >= thr.
//   P2: strip list (regs, no re-read) -> gather 64 B chunk rows of passing strips only,
//       filter chunks >= thr (overflow -> full scan, P~0).
//   P3: batched fp32-exact rescore, 16 lanes/chunk, one key/lane.
//   P4: wave extraction + block merge -> softmax / gather / normalize.
__global__ __launch_bounds__(256, 8) void finalize_batch(
    const _Float16* __restrict__ candT, const _Float16* __restrict__ candS,
    const float* __restrict__ mem, const float* __restrict__ qn,
    const int* __restrict__ index_map, const int* __restrict__ excl,
    float* __restrict__ outR, float* __restrict__ outD, float* __restrict__ outW, int N) {
    const int q = blockIdx.x, t = threadIdx.x;
    const int w = t >> 6, lane = t & 63;

    __shared__ float sQ[D128];
    __shared__ float sMrg[4 * 6];
    __shared__ float sThr;
    __shared__ unsigned short sStr[NSTRIP];
    __shared__ int sNs;
    __shared__ unsigned short sChk[CAP];
    __shared__ int sCnt, sOv;
    __shared__ float sWv[4 * TOPK];
    __shared__ int   sWk[4 * TOPK];
    __shared__ float sW[TOPK];
    __shared__ int   sJ[TOPK];

    if (t < 128) sQ[t] = qn[(size_t)q * D128 + t];
    if (t == 0) { sNs = 0; sCnt = 0; sOv = 0; }

    // strip maxima for strips t and t+256 (others = -inf)
    float v0 = (t < NSTRIP) ? (float)candS[(size_t)t * 1024 + q] : -3e38f;
    float v1 = (t + 256 < NSTRIP) ? (float)candS[(size_t)(t + 256) * 1024 + q] : -3e38f;

    // ---- P1: block 6th-largest strip max ----
    float pv[6];
    #pragma unroll
    for (int i = 0; i < 6; ++i) pv[i] = -3e38f;
    if (v0 > pv[5]) insertv<6>(pv, v0);
    if (v1 > pv[5]) insertv<6>(pv, v1);
    #pragma unroll
    for (int r = 0; r < 6; ++r) {
        float bv = pv[0];
        #pragma unroll
        for (int off = 32; off > 0; off >>= 1) bv = fmaxf(bv, __shfl_xor(bv, off, 64));
        int ml = (pv[0] == bv) ? lane : 64;
        #pragma unroll
        for (int off = 32; off > 0; off >>= 1) ml = min(ml, __shfl_xor(ml, off, 64));
        if (lane == ml) {
            #pragma unroll
            for (int i = 0; i < 5; ++i) pv[i] = pv[i + 1];
            pv[5] = -3e38f;
        }
        if (lane == 0) sMrg[w * 6 + r] = bv;
    }
    __syncthreads();
    if (t == 0) {
        float b6[6];
        #pragma unroll
        for (int i = 0; i < 6; ++i) b6[i] = -3e38f;
        for (int j = 0; j < 24; ++j) {
            float v = sMrg[j];
            if (v > b6[5]) insertv<6>(b6, v);
        }
        sThr = b6[5] - 2.0f * MARGIN;
    }
    __syncthreads();
    const float thr = sThr;

    // ---- P2a: strip list (from registers) ----
    if (t < NSTRIP && v0 >= thr) { int p = atomicAdd(&sNs, 1); sStr[p] = (unsigned short)t; }
    if (t + 256 < NSTRIP && v1 >= thr) { int p = atomicAdd(&sNs, 1); sStr[p] = (unsigned short)(t + 256); }
    __syncthreads();
    const int ns = sNs;

    // ---- P2b: gather chunk rows of passing strips (8 strips x 32 lanes per iter) ----
    const _Float16* crow = candT + (size_t)q * NCH2;
    for (int base = 0; base < ns; base += 8) {
        int gi = base + (t >> 5);
        if (gi < ns) {
            int ch = (int)sStr[gi] * 32 + (t & 31);
            if ((float)crow[ch] >= thr) {
                int p = atomicAdd(&sCnt, 1);
                if (p < CAP) sChk[p] = (unsigned short)ch; else sOv = 1;
            }
        }
    }
    __syncthreads();
    const int ov = sOv;
    const int cnt = ov ? NCH2 : min(sCnt, CAP);

    // ---- P3: batched fp32-exact rescore (16 chunks per round) ----
    const int exq = excl[q];
    float tv[TOPK]; int ti[TOPK];
    #pragma unroll
    for (int i = 0; i < TOPK; ++i) { tv[i] = -3e38f; ti[i] = -1; }
    const int rounds = (cnt + 15) >> 4;
    for (int r = 0; r < rounds; ++r) {
        int slot = r * 16 + (t >> 4);
        int ch = (slot < cnt) ? (ov ? slot : (int)sChk[slot]) : -1;
        int key = ch * 16 + (t & 15);
        float v = -3e38f;
        if (ch >= 0 && key < N && index_map[key] != exq) {
            const float4* mr = (const float4*)(mem + (size_t)key * D128);
            const float4* qv = (const float4*)sQ;
            float acc = 0.f;
            #pragma unroll
            for (int d = 0; d < 32; ++d) {
                float4 a = mr[d], b = qv[d];
                acc += a.x * b.x + a.y * b.y + a.z * b.z + a.w * b.w;
            }
            v = acc;
        }
        if (v > tv[TOPK - 1]) insertg<TOPK>(tv, ti, v, key);
    }

    // ---- P4: wave extraction (tie-break smaller key), block merge, outputs ----
    #pragma unroll
    for (int r = 0; r < TOPK; ++r) {
        float bv = tv[0]; int bk = ti[0];
        #pragma unroll
        for (int off = 32; off > 0; off >>= 1) {
            float ovv = __shfl_xor(bv, off, 64);
            int   okk = __shfl_xor(bk, off, 64);
            if (ovv > bv || (ovv == bv && (unsigned)okk < (unsigned)bk)) { bv = ovv; bk = okk; }
        }
        if (tv[0] == bv && ti[0] == bk) {
            #pragma unroll
            for (int i = 0; i < TOPK - 1; ++i) { tv[i] = tv[i + 1]; ti[i] = ti[i + 1]; }
            tv[TOPK - 1] = -3e38f; ti[TOPK - 1] = -1;
        }
        if (lane == 0) { sWv[w * TOPK + r] = bv; sWk[w * TOPK + r] = bk; }
    }
    __syncthreads();
    if (t == 0) {
        float bv[TOPK]; int bi[TOPK];
        #pragma unroll
        for (int i = 0; i < TOPK; ++i) { bv[i] = -3e38f; bi[i] = -1; }
        for (int j = 0; j < 4 * TOPK; ++j) {
            float v = sWv[j];
            if (v > bv[TOPK - 1]) insertg<TOPK>(bv, bi, v, sWk[j]);
        }
        float m = bv[0], ex[TOPK], sum = 0.f;
        #pragma unroll
        for (int k = 0; k < TOPK; ++k) { ex[k] = __expf((bv[k] - m) * 10.0f); sum += ex[k]; }
        float inv = 1.0f / sum;
        #pragma unroll
        for (int k = 0; k < TOPK; ++k) {
            float wk = ex[k] * inv;
            sW[k] = wk; sJ[k] = bi[k];
            outW[(size_t)q * TOPK + k] = wk;
        }
        outD[q] = 1.0f - bv[0];
    }
    __syncthreads();
    if (t < 64) {
        float r0 = 0.f, r1 = 0.f;
        #pragma unroll
        for (int k = 0; k < TOPK; ++k) {
            const float* mr = mem + (size_t)sJ[k] * D128;
            r0 += sW[k] * mr[t];
            r1 += sW[k] * mr[t + 64];
        }
        float ss = r0 * r0 + r1 * r1;
        #pragma unroll
        for (int off = 32; off > 0; off >>= 1) ss += __shfl_xor(ss, off, 64);
        float scale = 1.0f / fmaxf(sqrtf(ss), 1e-12f);
        outR[(size_t)q * D128 + t]      = r0 * scale;
        outR[(size_t)q * D128 + t + 64] = r1 * scale;
    }
}

extern "C" void kernel_launch(void* const* d_in, const int* in_sizes, int n_in,
                              void* d_out, int out_size, void* d_ws, size_t ws_size,
                              hipStream_t stream) {
    const float* query  = (const float*)d_in[0];   // [B,128] fp32
    const float* memory = (const float*)d_in[1];   // [N,128] fp32 (pre-normalized)
    const int* index_map = (const int*)d_in[2];    // [N] int32
    const int* excl      = (const int*)d_in[3];    // [B] int32

    const int B = in_sizes[3];                     // 1024
    const int N = in_sizes[2];                     // 200000

    // Workspace:
    //   qn    fp32 [B*128]          @ 0          (512 KB)
    //   qbf   bf16 [B*128]          @ 524288     (256 KB)
    //   mbf   bf16 [NP*128]         @ 786432     (51.4 MB)
    //   candT fp16 [B][NCH2]        @ 52166656   (25.7 MB)
    //   candS fp16 [NSTRIP][1024]   @ 77856768   (0.8 MB)   total ~78.7 MB
    char* ws = (char*)d_ws;
    float*    qn    = (float*)(ws);
    short*    qbf   = (short*)(ws + 524288);
    short*    mbf   = (short*)(ws + 786432);
    _Float16* candT = (_Float16*)(ws + 52166656);
    _Float16* candS = (_Float16*)(ws + 77856768);

    float* outR = (float*)d_out;                   // [B,128]
    float* outD = outR + (size_t)B * D128;         // [B]
    float* outW = outD + B;                        // [B,5]

    qnorm_kernel<<<B, 64, 0, stream>>>(query, qn, qbf);
    mconv_kernel<<<(NP * 16 + 255) / 256, 256, 0, stream>>>(memory, mbf, N);
    dim3 gridC(NSTRIP, 4);
    simtopk_max<<<gridC, 256, 0, stream>>>(qbf, mbf, candT, candS);
    finalize_batch<<<B, 256, 0, stream>>>(candT, candS, memory, qn, index_map, excl,
                                          outR, outD, outW, N);
}